// Round 4
// baseline (164.806 us; speedup 1.0000x reference)
//
#include <hip/hip_runtime.h>

// y = q_tok(x) @ q_grp(W)^T + bias, factored exactly:
//   q(x) = g_x * s_x[m], q(W) = g_w * s_w[n,grp] (grp=128 along K)
//   y[m,n] = s_x[m] * sum_grp s_w[n,grp] * (sum_{k in grp} g_x g_w)
// R9: gemm retiled 128x64 -> 64x64 (grid 2048 = 6 blocks/CU, was
// grid-capped at 4) for stall hiding; LDS swizzle period widened to 8
// rows (slot = (lq + row>>1) & 3) -- the old &3 rotation left a
// structural 2-way bank conflict (rows 4 apart repeat bank quads).
// Quant w-role: 16 elems/thread, 4096 blocks, uint2 stores.

#define M_TOK 2048
#define N_OUT 4096
#define K_IN  4096
#define KB    2048    // packed fp4 bytes per K row (K_IN/2)
#define XBLK  2048    // x-role: one block per token row
#define WBLK  4096    // w-role: one block per W row (4096 floats = 32 groups)

typedef __attribute__((ext_vector_type(4))) int   int4v;
typedef __attribute__((ext_vector_type(8))) int   int8v;
typedef __attribute__((ext_vector_type(4))) float floatx4;

// fp4-e2m1 nibble via scale-premultiplied decision thresholds
// T = {.25,.75,1.25,1.75,2.5,3.5,5}*scale; codes 0..7 = {0,.5,1,1.5,2,3,4,6}
__device__ __forceinline__ unsigned int q_nib(
    float v, float t0, float t1, float t2, float t3, float t4, float t5, float t6)
{
    float a = fabsf(v);
    unsigned int m =
        a < t0 ? 0u : a < t1 ? 1u : a < t2 ? 2u : a < t3 ? 3u :
        a < t4 ? 4u : a < t5 ? 5u : a < t6 ? 6u : 7u;
    return m | ((__float_as_uint(v) >> 28) & 0x8u);
}

#define MK_THR(scale) \
    const float t0 = 0.25f * (scale), t1 = 0.75f * (scale), \
                t2 = 1.25f * (scale), t3 = 1.75f * (scale), \
                t4 = 2.5f  * (scale), t5 = 3.5f  * (scale), \
                t6 = 5.0f  * (scale);

// ---------- fused quant: blocks [0,XBLK) per-token x, rest per-group w ----------
__global__ __launch_bounds__(256) void quant_fused_kernel(
    const float* __restrict__ x, const float* __restrict__ w,
    unsigned char* __restrict__ xq, float* __restrict__ sx,
    unsigned char* __restrict__ wq, float* __restrict__ swt)
{
    const int t = threadIdx.x;
    const int lane = t & 63, wid = t >> 6;

    if (blockIdx.x < XBLK) {
        // ---- per-token row of 4096: clamp [-3,3], scale = absmax/6 ----
        // coalesced: phase i loads float4 at i*1024 + t*4 (16B/lane contiguous)
        const int row = blockIdx.x;
        const float* xr = x + (size_t)row * K_IN;
        float4 v[4];
        float amax = 0.0f;
        #pragma unroll
        for (int i = 0; i < 4; i++) {
            float4 a = *(const float4*)(xr + i * 1024 + t * 4);
            a.x = fminf(fmaxf(a.x, -3.0f), 3.0f);
            a.y = fminf(fmaxf(a.y, -3.0f), 3.0f);
            a.z = fminf(fmaxf(a.z, -3.0f), 3.0f);
            a.w = fminf(fmaxf(a.w, -3.0f), 3.0f);
            v[i] = a;
            amax = fmaxf(amax, fmaxf(fmaxf(fabsf(a.x), fabsf(a.y)),
                                     fmaxf(fabsf(a.z), fabsf(a.w))));
        }
        #pragma unroll
        for (int off = 32; off; off >>= 1)
            amax = fmaxf(amax, __shfl_xor(amax, off));
        __shared__ float smax[4];
        if (lane == 0) smax[wid] = amax;
        __syncthreads();
        amax = fmaxf(fmaxf(smax[0], smax[1]), fmaxf(smax[2], smax[3]));

        const float scale = amax / 6.0f;
        if (t == 0) sx[row] = scale;
        MK_THR(scale);
        unsigned char* xo = xq + (size_t)row * KB;
        #pragma unroll
        for (int i = 0; i < 4; i++) {
            unsigned int u = q_nib(v[i].x, t0,t1,t2,t3,t4,t5,t6)
                           | (q_nib(v[i].y, t0,t1,t2,t3,t4,t5,t6) << 4)
                           | (q_nib(v[i].z, t0,t1,t2,t3,t4,t5,t6) << 8)
                           | (q_nib(v[i].w, t0,t1,t2,t3,t4,t5,t6) << 12);
            *(unsigned short*)(xo + i * 512 + t * 2) = (unsigned short)u;
        }
    } else {
        // ---- per-group w: block = one W row (4096 floats = 32 groups);
        //      8 lanes/group, 16 consecutive elements per lane -> uint2 ----
        const int b = blockIdx.x - XBLK;
        const float* base = w + (size_t)b * 4096 + t * 16;
        float vals[16];
        float amax = 0.0f;
        #pragma unroll
        for (int i = 0; i < 4; i++) {
            float4 a = *(const float4*)(base + i * 4);
            vals[i*4+0] = a.x; vals[i*4+1] = a.y;
            vals[i*4+2] = a.z; vals[i*4+3] = a.w;
            amax = fmaxf(amax, fmaxf(fmaxf(fabsf(a.x), fabsf(a.y)),
                                     fmaxf(fabsf(a.z), fabsf(a.w))));
        }
        #pragma unroll
        for (int off = 4; off; off >>= 1)   // reduce within 8-lane cluster
            amax = fmaxf(amax, __shfl_xor(amax, off));
        const float scale = amax / 6.0f;
        if ((t & 7) == 0)                    // group gk = t>>3 of row n = b
            swt[(size_t)(t >> 3) * N_OUT + b] = scale;
        MK_THR(scale);
        uint2 u;
        u.x = 0; u.y = 0;
        #pragma unroll
        for (int j = 0; j < 8; j++)
            u.x |= q_nib(vals[j], t0,t1,t2,t3,t4,t5,t6) << (4 * j);
        #pragma unroll
        for (int j = 0; j < 8; j++)
            u.y |= q_nib(vals[8 + j], t0,t1,t2,t3,t4,t5,t6) << (4 * j);
        *(uint2*)(wq + (size_t)b * 2048 + t * 8) = u;
    }
}

// ---------- async 16B global->LDS ----------
__device__ __forceinline__ void gld16(const unsigned char* g, unsigned char* l) {
    __builtin_amdgcn_global_load_lds(
        (const __attribute__((address_space(1))) void*)g,
        (__attribute__((address_space(3))) void*)l, 16, 0, 0);
}

// ---------- MX-fp4 GEMM, BK=128 = one quant group per MFMA ----------
// Tile 64x64, 4 waves (2m x 2n), wave tile 32x32, double-buffered LDS,
// counted vmcnt, static g&1 buffer index, setprio around MFMA cluster.
// 6 blocks/CU (24 KB LDS, <=85 VGPR).
__global__ __launch_bounds__(256, 6) void gemm_mx4_kernel(
    const unsigned char* __restrict__ A, const float* __restrict__ sx,
    const unsigned char* __restrict__ B, const float* __restrict__ swt,
    const float* __restrict__ bias, float* __restrict__ C)
{
    __shared__ __align__(16) unsigned char As[2][64 * 64];   // 2 x 4 KB
    __shared__ __align__(16) unsigned char Bs[2][64 * 64];   // 2 x 4 KB
    __shared__ __align__(16) float svs[32][64];              // 8 KB scales

    const int tid = threadIdx.x;
    const int m0 = blockIdx.y * 64;
    const int n0 = blockIdx.x * 64;
    const int lane = tid & 63;
    const int wid  = tid >> 6;
    const int wm = (wid & 1) * 32;   // wave m-offset: 0/32
    const int wn = (wid >> 1) * 32;  // wave n-offset: 0/32
    const int lr = lane & 15;
    const int lq = lane >> 4;

    floatx4 mast[2][2] = {};

    // staging: swizzle phys-slot = (c + (row>>1)) & 3 (8-row period so rows
    // 0..7 hit 8 distinct bank quads); inverse applied on the global source
    // so the LDS dest stays wave-uniform + lane*16.
    // 256 chunks(16B) per buffer per operand, 1/thread each.
    const unsigned char* gA;
    const unsigned char* gB;
    int ldst;
    {
        const int row = tid >> 2, ph = tid & 3;
        const int c = (ph - (row >> 1)) & 3;     // logical chunk at phys ph
        gA = A + (size_t)(m0 + row) * KB + c * 16;
        gB = B + (size_t)(n0 + row) * KB + c * 16;
        ldst = tid * 16;
    }

#define STAGE(gg, ss) do {                                     \
        const int koff_ = (gg) * 64;                           \
        gld16(gA + koff_, &As[ss][ldst]);                      \
        gld16(gB + koff_, &Bs[ss][ldst]);                      \
    } while (0)

    // one-time stage of this block's weight scales: swt[g][n0..n0+64)
    // (before STAGE(0) so the compiler's load-use waits don't drain gld16s)
    {
        float4 tmp[2];
        #pragma unroll
        for (int i = 0; i < 2; i++) {
            const int flat = tid + i * 256;      // float4 index, 512 total
            const int g = flat >> 4, c = (flat & 15) << 2;
            tmp[i] = *(const float4*)(swt + (size_t)g * N_OUT + n0 + c);
        }
        #pragma unroll
        for (int i = 0; i < 2; i++) {
            const int flat = tid + i * 256;
            const int g = flat >> 4, c = (flat & 15) << 2;
            *(float4*)&svs[g][c] = tmp[i];
        }
    }
    // prologue: stage k-group 0 into buffer 0
    STAGE(0, 0);
    asm volatile("s_waitcnt lgkmcnt(0)" ::: "memory");  // svs ds_writes done

    const floatx4 zero = {0.0f, 0.0f, 0.0f, 0.0f};

    #pragma unroll 2
    for (int g = 0; g < 32; g++) {
        const int cur = g & 1;
        if (g < 31) {
            // issue next tile's 2 loads; keep in flight -- wait only for
            // the 2 older loads (current buffer)
            STAGE(g + 1, cur ^ 1);
            asm volatile("s_waitcnt vmcnt(2)" ::: "memory");
        } else {
            asm volatile("s_waitcnt vmcnt(0)" ::: "memory");
        }
        __builtin_amdgcn_s_barrier();            // buf[cur] ready for all
        __builtin_amdgcn_sched_barrier(0);

        float sv[2];
        #pragma unroll
        for (int ni = 0; ni < 2; ni++)
            sv[ni] = svs[g][wn + ni * 16 + lr];

        // fragment reads: fp4 => one 16B chunk per fragment (32 elems/lane)
        int8v af[2], bf[2];
        #pragma unroll
        for (int mi = 0; mi < 2; mi++) {
            const int row = wm + mi * 16 + lr;
            const int slot = (lq + (row >> 1)) & 3;
            int4v d = *(const int4v*)&As[cur][row * 64 + slot * 16];
            af[mi] = (int8v){d[0], d[1], d[2], d[3], 0, 0, 0, 0};
        }
        #pragma unroll
        for (int ni = 0; ni < 2; ni++) {
            const int row = wn + ni * 16 + lr;
            const int slot = (lq + (row >> 1)) & 3;
            int4v d = *(const int4v*)&Bs[cur][row * 64 + slot * 16];
            bf[ni] = (int8v){d[0], d[1], d[2], d[3], 0, 0, 0, 0};
        }
        asm volatile("s_waitcnt lgkmcnt(0)" ::: "memory");
        __builtin_amdgcn_sched_barrier(0);       // rule #18: pin MFMA below
        __builtin_amdgcn_s_barrier();            // buf[cur] free for overwrite

        __builtin_amdgcn_s_setprio(1);
        #pragma unroll
        for (int mi = 0; mi < 2; mi++)
            #pragma unroll
            for (int ni = 0; ni < 2; ni++) {
                floatx4 tacc = __builtin_amdgcn_mfma_scale_f32_16x16x128_f8f6f4(
                    af[mi], bf[ni], zero, 4, 4,          // cbsz=blgp=4 -> fp4
                    0, 0x7F7F7F7F, 0, 0x7F7F7F7F);       // e8m0 scales = 1.0
                mast[mi][ni] += sv[ni] * tacc;
            }
        __builtin_amdgcn_s_setprio(0);
    }

    // epilogue: C/D layout col=lane&15, row=(lane>>4)*4+reg [m89/m91]
    #pragma unroll
    for (int mi = 0; mi < 2; mi++) {
        const int rbase = m0 + wm + mi * 16 + lq * 4;
        #pragma unroll
        for (int ni = 0; ni < 2; ni++) {
            const int cc = n0 + wn + ni * 16 + lr;
            const float bb = bias[cc];
            #pragma unroll
            for (int r = 0; r < 4; r++)
                C[(size_t)(rbase + r) * N_OUT + cc] =
                    sx[rbase + r] * mast[mi][ni][r] + bb;
        }
    }
#undef STAGE
}

extern "C" void kernel_launch(void* const* d_in, const int* in_sizes, int n_in,
                              void* d_out, int out_size, void* d_ws, size_t ws_size,
                              hipStream_t stream) {
    const float* x    = (const float*)d_in[0];
    const float* w    = (const float*)d_in[1];
    const float* bias = (const float*)d_in[2];
    float* out = (float*)d_out;

    unsigned char* xq = (unsigned char*)d_ws;                       // 4 MB
    unsigned char* wq = xq + (size_t)M_TOK * KB;                    // 8 MB
    float* swt = (float*)(wq + (size_t)N_OUT * KB);                 // 512 KB, [32][4096]
    float* sx  = swt + (size_t)(K_IN / 128) * N_OUT;                // 8 KB

    quant_fused_kernel<<<XBLK + WBLK, 256, 0, stream>>>(x, w, xq, sx, wq, swt);
    gemm_mx4_kernel<<<dim3(N_OUT / 64, M_TOK / 64), 256, 0, stream>>>(
        xq, sx, wq, swt, bias, out);
}